// Round 10
// baseline (29.914 us; speedup 1.0000x reference)
//
#include <hip/hip_runtime.h>

#define NCH   1024    // OUT_CH * IN_GROUP
#define KHW   64      // H*W = GEMM K
#define BPT   64      // points per block
#define BCH   256     // channels per block
#define CST   72      // Cl row stride (bf16)
#define WST   72      // Wl row stride (bf16)
#define SROW  260     // stage row stride in f32 words (1040 B; 8-words/bank optimal)

typedef __attribute__((ext_vector_type(8))) short          bf16x8;
typedef __attribute__((ext_vector_type(4))) float          f32x4;
typedef __attribute__((ext_vector_type(4))) int            i32x4;
typedef __attribute__((ext_vector_type(4))) unsigned short u16x4;

__device__ __forceinline__ unsigned short f2bf(float f) {
    unsigned int u = __float_as_uint(f);
    u += 0x7FFFu + ((u >> 16) & 1u);          // round-to-nearest-even
    return (unsigned short)(u >> 16);
}

__global__ __launch_bounds__(256)
void spline_gemm(const float* __restrict__ xy,
                 const float* __restrict__ C,
                 const float* __restrict__ Tx,
                 const float* __restrict__ Ty,
                 float* __restrict__ out,
                 int npts, int ntx, int nty) {
    // dynamic LDS: [ Cl: 256*72 bf16 = 36864 B ][ Wl: 64*72 bf16 = 9216 B ]
    // stage (64*260 f32 = 66560 B) aliases the whole region after MFMA reads
    extern __shared__ __align__(16) unsigned char lds[];
    unsigned short* Cl    = (unsigned short*)lds;
    unsigned short* Wl    = (unsigned short*)(lds + BCH * CST * 2);
    float*          stage = (float*)lds;

    const int t     = threadIdx.x;
    const int cgrp  = blockIdx.x & 3;      // 4 channel groups of 256
    const int pgrp  = blockIdx.x >> 2;     // 256 point groups of 64
    const int pbase = pgrp * BPT;
    const int cbase = cgrp * BCH;

    // ---- stage C slice (256 ch x 64 k = 16384 floats, 64/thread) -> bf16 LDS ----
    const float* Cb = C + (size_t)cbase * KHW;
    #pragma unroll
    for (int r = 0; r < 16; ++r) {
        const int fi = r * 1024 + t * 4;
        f32x4 v = *(const f32x4*)(Cb + fi);
        const int ch = fi >> 6, k = fi & 63;
        u16x4 w;
        w.x = f2bf(v.x); w.y = f2bf(v.y); w.z = f2bf(v.z); w.w = f2bf(v.w);
        *(u16x4*)&Cl[ch * CST + k] = w;
    }

    // ---- per-point weights (threads 0..63), self-zeroing row ----
    if (t < BPT) {
        const int n  = pbase + t;
        const int nc = min(n, npts - 1);
        float2 p = *(const float2*)(xy + 2 * nc);
        float X = p.x, Y = p.y;

        int kx = 2;
        for (int i = 3; i <= ntx - 4; ++i) kx += (Tx[i] <= X) ? 1 : 0;
        int ky = 2;
        for (int i = 3; i <= nty - 4; ++i) ky += (Ty[i] <= Y) ? 1 : 0;

        float tkm1 = Tx[kx - 1], tk = Tx[kx], tk1 = Tx[kx + 1], tk2 = Tx[kx + 2];
        float d;
        d = tk1 - tkm1; float a10 = (X - tkm1) / (d == 0.f ? 1.f : d);
        d = tk2 - tk;   float a11 = (X - tk)   / (d == 0.f ? 1.f : d);
        d = tk1 - tk;   float a21 = (X - tk)   / (d == 0.f ? 1.f : d);
        float wx0 = (1.f - a21) * (1.f - a10);
        float wx1 = (1.f - a21) * a10 + a21 * (1.f - a11);
        float wx2 = a21 * a11;

        tkm1 = Ty[ky - 1]; tk = Ty[ky]; tk1 = Ty[ky + 1]; tk2 = Ty[ky + 2];
        d = tk1 - tkm1; float b10 = (Y - tkm1) / (d == 0.f ? 1.f : d);
        d = tk2 - tk;   float b11 = (Y - tk)   / (d == 0.f ? 1.f : d);
        d = tk1 - tk;   float b21 = (Y - tk)   / (d == 0.f ? 1.f : d);
        float wy0 = (1.f - b21) * (1.f - b10);
        float wy1 = (1.f - b21) * b10 + b21 * (1.f - b11);
        float wy2 = b21 * b11;

        unsigned short* rowbase = &Wl[t * WST];
        i32x4 z = {0, 0, 0, 0};
        #pragma unroll
        for (int j = 0; j < 8; ++j) *(i32x4*)(rowbase + j * 8) = z;

        unsigned short* row = rowbase + (kx - 2) * 8 + (ky - 2);
        row[0]  = f2bf(wx0 * wy0); row[1]  = f2bf(wx0 * wy1); row[2]  = f2bf(wx0 * wy2);
        row[8]  = f2bf(wx1 * wy0); row[9]  = f2bf(wx1 * wy1); row[10] = f2bf(wx1 * wy2);
        row[16] = f2bf(wx2 * wy0); row[17] = f2bf(wx2 * wy1); row[18] = f2bf(wx2 * wy2);
    }
    __syncthreads();                               // barrier 1: Cl/Wl ready

    // ---- MFMA: 4 waves; wm = ch half (128), wn = pt half (32) ----
    const int wid  = t >> 6;
    const int lane = t & 63;
    const int wm   = wid & 1;
    const int wn   = wid >> 1;
    const int l15  = lane & 15;
    const int l4   = lane >> 4;

    f32x4 acc[8][2] = {};   // [mf: ch frag of 8][nf: pt frag of 2]
    {
        const unsigned short* Ab = Cl + (wm * 128 + l15) * CST + l4 * 8;
        const unsigned short* Bb = Wl + (wn * 32  + l15) * WST + l4 * 8;
        #pragma unroll
        for (int kr = 0; kr < 2; ++kr) {
            bf16x8 a[8], b[2];
            #pragma unroll
            for (int mf = 0; mf < 8; ++mf) a[mf] = *(const bf16x8*)(Ab + mf * 16 * CST + kr * 32);
            #pragma unroll
            for (int nf = 0; nf < 2; ++nf) b[nf] = *(const bf16x8*)(Bb + nf * 16 * WST + kr * 32);
            #pragma unroll
            for (int mf = 0; mf < 8; ++mf)
                #pragma unroll
                for (int nf = 0; nf < 2; ++nf)
                    acc[mf][nf] = __builtin_amdgcn_mfma_f32_16x16x32_bf16(
                                      a[mf], b[nf], acc[mf][nf], 0, 0, 0);
        }
    }
    __syncthreads();                               // barrier 2: Cl/Wl dead -> stage may alias

    // ---- acc -> stage: D col(l15)=point, row(l4*4+reg)=channel ----
    #pragma unroll
    for (int nf = 0; nf < 2; ++nf) {
        const int ptl = wn * 32 + nf * 16 + l15;
        float* sp = stage + ptl * SROW + wm * 128 + l4 * 4;
        #pragma unroll
        for (int mf = 0; mf < 8; ++mf)
            *(f32x4*)(sp + mf * 16) = acc[mf][nf];
    }
    __syncthreads();                               // barrier 3: stage complete

    // ---- contiguous store: wave wid streams pts [wid*16, wid*16+16) ----
    // one ds_read_b128 + one 1KB-contiguous global dwordx4 store per point
    #pragma unroll
    for (int q = 0; q < 16; ++q) {
        const int ptl = wid * 16 + q;
        const int pt  = pbase + ptl;
        f32x4 v = *(const f32x4*)(stage + ptl * SROW + lane * 4);
        if (pt < npts)
            *(f32x4*)(out + (size_t)pt * NCH + cbase + lane * 4) = v;
    }
}

extern "C" void kernel_launch(void* const* d_in, const int* in_sizes, int n_in,
                              void* d_out, int out_size, void* d_ws, size_t ws_size,
                              hipStream_t stream) {
    const float* xy = (const float*)d_in[0];
    const float* C  = (const float*)d_in[1];
    const float* Tx = (const float*)d_in[2];
    const float* Ty = (const float*)d_in[3];
    float* out = (float*)d_out;

    int npts = in_sizes[0] / 2;
    int ntx  = in_sizes[2];
    int nty  = in_sizes[3];

    int pgs = (npts + BPT - 1) / BPT;
    dim3 grid(pgs * 4);
    dim3 block(256);
    size_t lds_bytes = BPT * SROW * 4;   // 66560 B (stage; covers Cl+Wl region)
    hipLaunchKernelGGL(spline_gemm, grid, block, lds_bytes, stream,
                       xy, C, Tx, Ty, out, npts, ntx, nty);
}

// Round 11
// 24.258 us; speedup vs baseline: 1.2332x; 1.2332x over previous
//
#include <hip/hip_runtime.h>

#define NCH 1024      // OUT_CH * IN_GROUP
#define KHW 64        // H*W = GEMM K
#define BPT 64        // points per block (complete 4KB output rows)
#define WST 72        // Wl row stride in bf16

typedef __attribute__((ext_vector_type(8))) short bf16x8;
typedef __attribute__((ext_vector_type(4))) float f32x4;
typedef __attribute__((ext_vector_type(4))) int   i32x4;

__device__ __forceinline__ unsigned short f2bf(float f) {
    unsigned int u = __float_as_uint(f);
    u += 0x7FFFu + ((u >> 16) & 1u);          // round-to-nearest-even
    return (unsigned short)(u >> 16);
}

__global__ __launch_bounds__(512, 2)
void spline_gemm(const float* __restrict__ xy,
                 const float* __restrict__ C,
                 const float* __restrict__ Tx,
                 const float* __restrict__ Ty,
                 float* __restrict__ out,
                 int npts, int ntx, int nty) {
    __shared__ __align__(16) unsigned short Wl[BPT * WST];   // 9 KB point weights

    const int t     = threadIdx.x;
    const int pbase = blockIdx.x * BPT;

    const int wid  = t >> 6;       // 0..7 -> channel slice [wid*128, wid*128+128)
    const int lane = t & 63;
    const int l15  = lane & 15;
    const int l4   = lane >> 4;

    // ---- wave 0: per-point weights (one point per lane), self-zeroing row ----
    if (t < BPT) {
        const int n  = pbase + t;
        const int nc = min(n, npts - 1);
        float2 p = *(const float2*)(xy + 2 * nc);
        float X = p.x, Y = p.y;

        int kx = 2;
        for (int i = 3; i <= ntx - 4; ++i) kx += (Tx[i] <= X) ? 1 : 0;
        int ky = 2;
        for (int i = 3; i <= nty - 4; ++i) ky += (Ty[i] <= Y) ? 1 : 0;

        float tkm1 = Tx[kx - 1], tk = Tx[kx], tk1 = Tx[kx + 1], tk2 = Tx[kx + 2];
        float d;
        d = tk1 - tkm1; float a10 = (X - tkm1) / (d == 0.f ? 1.f : d);
        d = tk2 - tk;   float a11 = (X - tk)   / (d == 0.f ? 1.f : d);
        d = tk1 - tk;   float a21 = (X - tk)   / (d == 0.f ? 1.f : d);
        float wx0 = (1.f - a21) * (1.f - a10);
        float wx1 = (1.f - a21) * a10 + a21 * (1.f - a11);
        float wx2 = a21 * a11;

        tkm1 = Ty[ky - 1]; tk = Ty[ky]; tk1 = Ty[ky + 1]; tk2 = Ty[ky + 2];
        d = tk1 - tkm1; float b10 = (Y - tkm1) / (d == 0.f ? 1.f : d);
        d = tk2 - tk;   float b11 = (Y - tk)   / (d == 0.f ? 1.f : d);
        d = tk1 - tk;   float b21 = (Y - tk)   / (d == 0.f ? 1.f : d);
        float wy0 = (1.f - b21) * (1.f - b10);
        float wy1 = (1.f - b21) * b10 + b21 * (1.f - b11);
        float wy2 = b21 * b11;

        unsigned short* rowbase = &Wl[t * WST];
        i32x4 z = {0, 0, 0, 0};
        #pragma unroll
        for (int j = 0; j < 8; ++j) *(i32x4*)(rowbase + j * 8) = z;

        unsigned short* row = rowbase + (kx - 2) * 8 + (ky - 2);
        row[0]  = f2bf(wx0 * wy0); row[1]  = f2bf(wx0 * wy1); row[2]  = f2bf(wx0 * wy2);
        row[8]  = f2bf(wx1 * wy0); row[9]  = f2bf(wx1 * wy1); row[10] = f2bf(wx1 * wy2);
        row[16] = f2bf(wx2 * wy0); row[17] = f2bf(wx2 * wy1); row[18] = f2bf(wx2 * wy2);
    }

    // ---- all waves: C fragments for own 128-ch slice -> registers (bf16) ----
    // ch = wid*128 + mf*16 + l15 ; k = l4*8 + kr*32 (C is [ch][k], L2-resident)
    bf16x8 a[2][8];   // [kr][mf]
    {
        const float* Cb = C + (size_t)(wid * 128 + l15) * KHW + l4 * 8;
        #pragma unroll
        for (int kr = 0; kr < 2; ++kr) {
            #pragma unroll
            for (int mf = 0; mf < 8; ++mf) {
                const float* s = Cb + mf * 16 * KHW + kr * 32;
                f32x4 f0 = *(const f32x4*)s;
                f32x4 f1 = *(const f32x4*)(s + 4);
                bf16x8 bb;
                bb[0] = (short)f2bf(f0.x); bb[1] = (short)f2bf(f0.y);
                bb[2] = (short)f2bf(f0.z); bb[3] = (short)f2bf(f0.w);
                bb[4] = (short)f2bf(f1.x); bb[5] = (short)f2bf(f1.y);
                bb[6] = (short)f2bf(f1.z); bb[7] = (short)f2bf(f1.w);
                a[kr][mf] = bb;
            }
        }
    }
    __syncthreads();   // the ONLY barrier (Wl ready)

    // ---- MFMA: wave = 128 ch x 64 pts ----
    f32x4 acc[8][4] = {};   // [mf: ch frag][nf: pt frag]
    #pragma unroll
    for (int kr = 0; kr < 2; ++kr) {
        bf16x8 b[4];
        const unsigned short* Bb = Wl + l15 * WST + l4 * 8 + kr * 32;
        #pragma unroll
        for (int nf = 0; nf < 4; ++nf) b[nf] = *(const bf16x8*)(Bb + nf * 16 * WST);
        #pragma unroll
        for (int mf = 0; mf < 8; ++mf)
            #pragma unroll
            for (int nf = 0; nf < 4; ++nf)
                acc[mf][nf] = __builtin_amdgcn_mfma_f32_16x16x32_bf16(
                                  a[kr][mf], b[nf], acc[mf][nf], 0, 0, 0);
    }

    // ---- stores: pt rows completed by the block's 8 waves together ----
    // D: col(l15)=point, row(l4*4+reg)=channel -> dwordx4 per (mf,nf)
    #pragma unroll
    for (int nf = 0; nf < 4; ++nf) {
        const int pt = pbase + nf * 16 + l15;
        float* op = out + (size_t)pt * NCH + wid * 128 + l4 * 4;
        if (pt < npts) {
            #pragma unroll
            for (int mf = 0; mf < 8; ++mf)
                *(f32x4*)(op + mf * 16) = acc[mf][nf];
        }
    }
}

extern "C" void kernel_launch(void* const* d_in, const int* in_sizes, int n_in,
                              void* d_out, int out_size, void* d_ws, size_t ws_size,
                              hipStream_t stream) {
    const float* xy = (const float*)d_in[0];
    const float* C  = (const float*)d_in[1];
    const float* Tx = (const float*)d_in[2];
    const float* Ty = (const float*)d_in[3];
    float* out = (float*)d_out;

    int npts = in_sizes[0] / 2;
    int ntx  = in_sizes[2];
    int nty  = in_sizes[3];

    int pgs = (npts + BPT - 1) / BPT;
    dim3 grid(pgs);
    dim3 block(512);
    hipLaunchKernelGGL(spline_gemm, grid, block, 0, stream,
                       xy, C, Tx, Ty, out, npts, ntx, nty);
}

// Round 12
// 19.775 us; speedup vs baseline: 1.5127x; 1.2267x over previous
//
#include <hip/hip_runtime.h>

#define NCH 1024      // OUT_CH * IN_GROUP
#define KHW 64        // H*W = GEMM K
#define BPT 128       // points per block
#define BCH 128       // channels per block
#define WST 72        // Wl row stride in bf16 (144 B, 16B-aligned)
#define CST 72        // Cl row stride in bf16

typedef __attribute__((ext_vector_type(8))) short          bf16x8;
typedef __attribute__((ext_vector_type(4))) float          f32x4;
typedef __attribute__((ext_vector_type(4))) int            i32x4;
typedef __attribute__((ext_vector_type(4))) unsigned short u16x4;

__device__ __forceinline__ unsigned short f2bf(float f) {
    unsigned int u = __float_as_uint(f);
    u += 0x7FFFu + ((u >> 16) & 1u);          // round-to-nearest-even
    return (unsigned short)(u >> 16);
}

__global__ __launch_bounds__(256, 4)
void spline_gemm(const float* __restrict__ xy,
                 const float* __restrict__ C,
                 const float* __restrict__ Tx,
                 const float* __restrict__ Ty,
                 float* __restrict__ out,
                 int npts, int ntx, int nty) {
    __shared__ __align__(16) unsigned short Cl[BCH * CST];   // 18 KB C slice (bf16)
    __shared__ __align__(16) unsigned short Wl[BPT * WST];   // 18 KB point weights

    const int t     = threadIdx.x;
    const int cgrp  = blockIdx.x & 7;      // 8 channel groups -> XCD-pinned
    const int pgrp  = blockIdx.x >> 3;     // 128 point groups of 128 points
    const int pbase = pgrp * BPT;
    const int cbase = cgrp * BCH;

    // ---- role-split prologue: t<128 weights  ||  t>=128 C-stage ----
    if (t < BPT) {
        // per-point quadratic B-spline weights, one point per thread
        const int n  = pbase + t;
        const int nc = min(n, npts - 1);
        float2 p = *(const float2*)(xy + 2 * nc);
        float X = p.x, Y = p.y;

        int kx = 2;
        for (int i = 3; i <= ntx - 4; ++i) kx += (Tx[i] <= X) ? 1 : 0;
        int ky = 2;
        for (int i = 3; i <= nty - 4; ++i) ky += (Ty[i] <= Y) ? 1 : 0;

        float tkm1 = Tx[kx - 1], tk = Tx[kx], tk1 = Tx[kx + 1], tk2 = Tx[kx + 2];
        float d;
        d = tk1 - tkm1; float a10 = (X - tkm1) / (d == 0.f ? 1.f : d);
        d = tk2 - tk;   float a11 = (X - tk)   / (d == 0.f ? 1.f : d);
        d = tk1 - tk;   float a21 = (X - tk)   / (d == 0.f ? 1.f : d);
        float wx0 = (1.f - a21) * (1.f - a10);
        float wx1 = (1.f - a21) * a10 + a21 * (1.f - a11);
        float wx2 = a21 * a11;

        tkm1 = Ty[ky - 1]; tk = Ty[ky]; tk1 = Ty[ky + 1]; tk2 = Ty[ky + 2];
        d = tk1 - tkm1; float b10 = (Y - tkm1) / (d == 0.f ? 1.f : d);
        d = tk2 - tk;   float b11 = (Y - tk)   / (d == 0.f ? 1.f : d);
        d = tk1 - tk;   float b21 = (Y - tk)   / (d == 0.f ? 1.f : d);
        float wy0 = (1.f - b21) * (1.f - b10);
        float wy1 = (1.f - b21) * b10 + b21 * (1.f - b11);
        float wy2 = b21 * b11;

        // zero own row (8 x 16B) then scatter the 9 taps
        unsigned short* rowbase = &Wl[t * WST];
        i32x4 z = {0, 0, 0, 0};
        #pragma unroll
        for (int j = 0; j < 8; ++j) *(i32x4*)(rowbase + j * 8) = z;

        unsigned short* row = rowbase + (kx - 2) * 8 + (ky - 2);
        row[0]  = f2bf(wx0 * wy0); row[1]  = f2bf(wx0 * wy1); row[2]  = f2bf(wx0 * wy2);
        row[8]  = f2bf(wx1 * wy0); row[9]  = f2bf(wx1 * wy1); row[10] = f2bf(wx1 * wy2);
        row[16] = f2bf(wx2 * wy0); row[17] = f2bf(wx2 * wy1); row[18] = f2bf(wx2 * wy2);
    } else {
        // stage C slice (128 ch x 64 k = 8192 floats) -> bf16 LDS, 64 floats/thread
        const int tt = t - BPT;
        const float* Cb = C + (size_t)cbase * KHW;
        #pragma unroll
        for (int r = 0; r < 16; ++r) {
            const int fi = r * 512 + tt * 4;
            f32x4 v = *(const f32x4*)(Cb + fi);
            const int ch = fi >> 6, k = fi & 63;
            u16x4 w;
            w.x = f2bf(v.x); w.y = f2bf(v.y); w.z = f2bf(v.z); w.w = f2bf(v.w);
            *(u16x4*)&Cl[ch * CST + k] = w;
        }
    }
    __syncthreads();   // the ONLY barrier

    // ---- 4 waves: wm = ch half (64), wn = pt half (64); 32 MFMA + 16 stores ----
    const int wid  = t >> 6;
    const int lane = t & 63;
    const int wm   = wid & 1;
    const int wn   = wid >> 1;
    const int l15  = lane & 15;
    const int l4   = lane >> 4;

    const unsigned short* Ab = Cl + (wm * 64 + l15) * CST + l4 * 8;
    const unsigned short* Bb = Wl + (wn * 64 + l15) * WST + l4 * 8;

    f32x4 acc[4][4] = {};
    #pragma unroll
    for (int kr = 0; kr < 2; ++kr) {
        bf16x8 a[4], b[4];
        #pragma unroll
        for (int mf = 0; mf < 4; ++mf) a[mf] = *(const bf16x8*)(Ab + mf * 16 * CST + kr * 32);
        #pragma unroll
        for (int nf = 0; nf < 4; ++nf) b[nf] = *(const bf16x8*)(Bb + nf * 16 * WST + kr * 32);
        #pragma unroll
        for (int mf = 0; mf < 4; ++mf)
            #pragma unroll
            for (int nf = 0; nf < 4; ++nf)
                acc[mf][nf] = __builtin_amdgcn_mfma_f32_16x16x32_bf16(
                                  a[mf], b[nf], acc[mf][nf], 0, 0, 0);
    }

    // ---- stores: lane's 4 acc regs = 4 consecutive channels -> dwordx4 ----
    #pragma unroll
    for (int nf = 0; nf < 4; ++nf) {
        const int pt = pbase + wn * 64 + nf * 16 + l15;
        float* op = out + (size_t)pt * NCH + cbase + wm * 64 + l4 * 4;
        if (pt < npts) {
            #pragma unroll
            for (int mf = 0; mf < 4; ++mf)
                *(f32x4*)(op + mf * 16) = acc[mf][nf];
        }
    }
}

extern "C" void kernel_launch(void* const* d_in, const int* in_sizes, int n_in,
                              void* d_out, int out_size, void* d_ws, size_t ws_size,
                              hipStream_t stream) {
    const float* xy = (const float*)d_in[0];
    const float* C  = (const float*)d_in[1];
    const float* Tx = (const float*)d_in[2];
    const float* Ty = (const float*)d_in[3];
    float* out = (float*)d_out;

    int npts = in_sizes[0] / 2;
    int ntx  = in_sizes[2];
    int nty  = in_sizes[3];

    int pgs = (npts + BPT - 1) / BPT;
    dim3 grid(pgs * 8);
    dim3 block(256);
    hipLaunchKernelGGL(spline_gemm, grid, block, 0, stream,
                       xy, C, Tx, Ty, out, npts, ntx, nty);
}